// Round 14
// baseline (283.551 us; speedup 1.0000x reference)
//
#include <hip/hip_runtime.h>
#include <hip/hip_bf16.h>
#include <stdint.h>

#define M_TOK 32768
#define DIM   1024
#define ODIM  1024
#define NEXP  4
#define KTOT  4096            // NEXP * DIM (Wt row length)
#define NBIN  16              // expert-pair groups (e0*4+e1)
#define BM    256
#define BK    64
#define NT    (DIM / BK)      // 16 K-tiles
#define MTILES 144            // ceil((32768 + 16*255)/256) -> 144 (mult of 8)
#define PERM_LEN (MTILES * 256)   // 36864
#define GEMM_GRID (MTILES * 16)   // 2304 = 8 xcd * 18 mtiles * 16 nblk

typedef unsigned short u16;
typedef __bf16 bf16x8 __attribute__((ext_vector_type(8)));
typedef float  f32x4  __attribute__((ext_vector_type(4)));

__device__ inline u16 f2bf(float f) {
  union { float f; unsigned u; } v; v.f = f;
  unsigned u = v.u;
  unsigned r = u + 0x7FFFu + ((u >> 16) & 1u);
  return (u16)(r >> 16);
}

__device__ inline unsigned pack2(float lo, float hi) {
  return (unsigned)f2bf(lo) | ((unsigned)f2bf(hi) << 16);
}

__device__ inline void async16(const void* g, void* l) {
  __builtin_amdgcn_global_load_lds(
      (const __attribute__((address_space(1))) unsigned int*)g,
      (__attribute__((address_space(3))) unsigned int*)l, 16, 0, 0);
}

// ---- pre-pass 1: x fp32 -> bf16 ----
__global__ void cvt_x(const float4* __restrict__ x, uint4* __restrict__ xb, int n8) {
  int i = blockIdx.x * blockDim.x + threadIdx.x;
  int stride = gridDim.x * blockDim.x;
  for (; i < n8; i += stride) {
    float4 a = x[2 * i];
    float4 b = x[2 * i + 1];
    uint4 o;
    o.x = pack2(a.x, a.y); o.y = pack2(a.z, a.w);
    o.z = pack2(b.x, b.y); o.w = pack2(b.z, b.w);
    xb[i] = o;
  }
}

// ---- pre-pass 2: W (E*D=4096, O=1024) fp32 -> Wt (O=1024, E*D=4096) bf16 ----
__global__ void cvt_wt(const float* __restrict__ W, u16* __restrict__ Wt) {
  __shared__ float t[32][33];
  int kk0 = blockIdx.x * 32, n0 = blockIdx.y * 32;
  int tx = threadIdx.x, ty = threadIdx.y;  // block (32,8)
#pragma unroll
  for (int j = 0; j < 32; j += 8)
    t[ty + j][tx] = W[(size_t)(kk0 + ty + j) * ODIM + n0 + tx];
  __syncthreads();
#pragma unroll
  for (int j = 0; j < 32; j += 8)
    Wt[(size_t)(n0 + ty + j) * KTOT + kk0 + tx] = f2bf(t[tx][ty + j]);
}

// ---- sort pipeline: ctrl[0..15]=count(bin), ctrl[16..31]=padded offset/cursor ----
__global__ void init_ctrl(int* __restrict__ ctrl, int* __restrict__ perm) {
  int i = blockIdx.x * blockDim.x + threadIdx.x;
  if (i < 32) ctrl[i] = 0;
  for (int j = i; j < PERM_LEN; j += gridDim.x * blockDim.x) perm[j] = -1;
}

__global__ void hist(const int* __restrict__ tki, int* __restrict__ ctrl) {
  __shared__ int h[NBIN];
  int tid = threadIdx.x;
  if (tid < NBIN) h[tid] = 0;
  __syncthreads();
  int t = blockIdx.x * 256 + tid;   // 128 blocks x 256 = 32768 tokens
  int e0 = tki[2 * t] & 3, e1 = tki[2 * t + 1] & 3;
  atomicAdd(&h[e0 * 4 + e1], 1);
  __syncthreads();
  if (tid < NBIN) atomicAdd(&ctrl[tid], h[tid]);
}

__global__ void plan(int* __restrict__ ctrl) {
  if (threadIdx.x == 0 && blockIdx.x == 0) {
    int off = 0;
#pragma unroll
    for (int b = 0; b < NBIN; ++b) {
      ctrl[16 + b] = off;
      off += (ctrl[b] + 255) & ~255;   // pad each pair-group to BM=256 rows
    }
  }
}

__global__ void scatter(const int* __restrict__ tki, const float* __restrict__ ew,
                        int* __restrict__ ctrl,
                        int* __restrict__ perm, float2* __restrict__ wgt2) {
  __shared__ int h[NBIN], gbase[NBIN], cur[NBIN];
  int tid = threadIdx.x;
  if (tid < NBIN) { h[tid] = 0; cur[tid] = 0; }
  __syncthreads();
  int t = blockIdx.x * 256 + tid;
  int e0 = tki[2 * t] & 3, e1 = tki[2 * t + 1] & 3;
  int bin = e0 * 4 + e1;
  atomicAdd(&h[bin], 1);
  __syncthreads();
  if (tid < NBIN && h[tid] > 0) gbase[tid] = atomicAdd(&ctrl[16 + tid], h[tid]);
  __syncthreads();
  int rank = atomicAdd(&cur[bin], 1);
  int pos = gbase[bin] + rank;
  perm[pos] = t;
  float2 w; w.x = ew[2 * t]; w.y = ew[2 * t + 1];
  wgt2[pos] = w;
}

// ---- fused pair-grouped GEMM, m201-style 4-phase pipeline w/ counted vmcnt ----
// out[t] = w0*(x@W_e0+b_e0) + w1*(x@W_e1+b_e1).
// BM=256 tokens x 64 cols (x2 experts), BK=64, 512 thr = 8 waves (4M x 2N),
// wave-tile 64x32 per expert. LDS: A dbuf 64K + B dbuf 32K + meta -> 1 blk/CU.
// Per K-tile: 4 phases (expert x kk), each {ds_read || stage-issue; s_barrier;
// lgkmcnt(0); setprio(1); 8 MFMA; setprio(0); s_barrier}. Staging of K-tile
// t+2's A+B0 issued in phase 3 (regions dead after phase 2), t+1's B1 in
// phase 0 (dead after prev iter). Single s_waitcnt vmcnt(5) per K-tile —
// prefetch loads stay in flight across barriers (T4). Raw s_barrier only
// (never __syncthreads in the loop — it would drain vmcnt to 0).
__global__ __launch_bounds__(512, 1) void moe_gemm(
    const u16* __restrict__ Xb,       // [M_TOK][DIM] bf16
    const u16* __restrict__ Wt,       // [ODIM][KTOT] bf16
    const int* __restrict__ perm,     // [PERM_LEN] token ids (-1 pad)
    const float2* __restrict__ wgt2,  // [PERM_LEN] (w0,w1)
    const int* __restrict__ tki,      // [M_TOK][2] expert ids
    const float* __restrict__ bias,   // [NEXP][ODIM] fp32
    float* __restrict__ out)          // [M_TOK][ODIM] fp32
{
  __shared__ __align__(16) u16 As[2][BM * BK];      // 2 x 32 KB
  __shared__ __align__(16) u16 Bs[2][2][64 * BK];   // 2 x 2 x 8 KB
  __shared__ int    rowsS[BM];
  __shared__ float2 wgtS[BM];

  // XCD remap: each XCD owns a contiguous run of 18 mtiles; the 16 nblk of
  // one mtile are concurrent on that XCD (A-panel + one W-panel L2-resident).
  const int d = blockIdx.x;
  const int slot = d >> 3;                  // 0..287
  const int mtile = (d & 7) * (MTILES / 8) + (slot >> 4);
  const int nblk = slot & 15;               // 16 N-blocks of 64 cols
  const int base = mtile * BM;
  const int t0 = perm[base];
  if (t0 < 0) return;                       // fully-padding tile (uniform)
  const int e0 = tki[2 * t0] & 3, e1 = tki[2 * t0 + 1] & 3;

  const int tid = threadIdx.x;
  if (tid < BM) { rowsS[tid] = perm[base + tid]; wgtS[tid] = wgt2[base + tid]; }

  const int wid = tid >> 6, lane = tid & 63;
  const int bcol = nblk * 64;
  const int wr = wid >> 1, wc = wid & 1;    // 4M x 2N; wave-tile 64 rows x 32 cols
  const int fcol = bcol + wc * 32;

  f32x4 acc0[4][2], acc1[4][2];
#pragma unroll
  for (int m = 0; m < 4; ++m)
#pragma unroll
    for (int n = 0; n < 2; ++n) {
      acc0[m][n] = (f32x4){0.f, 0.f, 0.f, 0.f};
      acc1[m][n] = (f32x4){0.f, 0.f, 0.f, 0.f};
    }

  const int srow = lane >> 3;                // 0..7
  const int scol = ((lane & 7) ^ srow) * 8;  // pre-swizzled source col (elems)
  const int hi16 = (lane >> 4) * 16;
  const int swz  = (lane & 7) << 4;

  __syncthreads();                           // meta ready (before pipeline: OK)

  // staging pointers: 4 A-chunks (32 chunks of 8 rows / 8 waves) + 1 B0 + 1 B1
  const u16* aptr[4];
#pragma unroll
  for (int i = 0; i < 4; ++i) {
    int c = wid * 4 + i;                     // 0..31: A rows c*8+srow (0..255)
    int r = rowsS[c * 8 + srow];
    if (r < 0) r = 0;                        // pad row: stage row 0, discard later
    aptr[i] = Xb + (size_t)r * DIM + scol;
  }
  const u16* b0ptr = Wt + (size_t)(bcol + wid * 8 + srow) * KTOT + e0 * DIM + scol;
  const u16* b1ptr = Wt + (size_t)(bcol + wid * 8 + srow) * KTOT + e1 * DIM + scol;

#define STAGE_AB0(bb, kt) do {                                          \
    _Pragma("unroll")                                                   \
    for (int i_ = 0; i_ < 4; ++i_)                                      \
      async16(aptr[i_] + (kt) * 64, &As[bb][(wid * 4 + i_) * 512]);     \
    async16(b0ptr + (kt) * 64, &Bs[bb][0][wid * 512]);                  \
  } while (0)
#define STAGE_B1(bb, kt) async16(b1ptr + (kt) * 64, &Bs[bb][1][wid * 512])
#define SBAR() __builtin_amdgcn_s_barrier()
#define LGKM0() do { asm volatile("s_waitcnt lgkmcnt(0)" ::: "memory"); \
                     __builtin_amdgcn_sched_barrier(0); } while (0)

  // prologue: t0 fully into buf0; t1's A+B0 into buf1; wait t0 landed.
  STAGE_AB0(0, 0);
  STAGE_B1(0, 0);
  STAGE_AB0(1, 1);
  asm volatile("s_waitcnt vmcnt(5)" ::: "memory");
  SBAR();

  const int arow0 = wr * 64 + (lane & 15);
  const int brow0 = wc * 32 + (lane & 15);

  for (int kt = 0; kt < NT; ++kt) {
    const int b = kt & 1;
    const char* Ab  = (const char*)As[b];
    const char* B0b = (const char*)Bs[b][0];
    const char* B1b = (const char*)Bs[b][1];
    const int cb0 = hi16 ^ swz;
    const int cb1 = (64 + hi16) ^ swz;
    bf16x8 af[4], bfr[2];

    // ---- phase 0: exp0, kk0. Issue t+1's B1 into B1[b^1] (dead region).
#pragma unroll
    for (int m = 0; m < 4; ++m)
      af[m] = *reinterpret_cast<const bf16x8*>(Ab + (arow0 + m * 16) * 128 + cb0);
#pragma unroll
    for (int n = 0; n < 2; ++n)
      bfr[n] = *reinterpret_cast<const bf16x8*>(B0b + (brow0 + n * 16) * 128 + cb0);
    if (kt + 1 < NT) STAGE_B1(b ^ 1, kt + 1);
    SBAR();
    LGKM0();
    __builtin_amdgcn_s_setprio(1);
#pragma unroll
    for (int m = 0; m < 4; ++m)
#pragma unroll
      for (int n = 0; n < 2; ++n)
        acc0[m][n] = __builtin_amdgcn_mfma_f32_16x16x32_bf16(af[m], bfr[n], acc0[m][n], 0, 0, 0);
    __builtin_amdgcn_s_setprio(0);
    SBAR();

    // ---- phase 1: exp1, kk0 (reuse af).
#pragma unroll
    for (int n = 0; n < 2; ++n)
      bfr[n] = *reinterpret_cast<const bf16x8*>(B1b + (brow0 + n * 16) * 128 + cb0);
    SBAR();
    LGKM0();
    __builtin_amdgcn_s_setprio(1);
#pragma unroll
    for (int m = 0; m < 4; ++m)
#pragma unroll
      for (int n = 0; n < 2; ++n)
        acc1[m][n] = __builtin_amdgcn_mfma_f32_16x16x32_bf16(af[m], bfr[n], acc1[m][n], 0, 0, 0);
    __builtin_amdgcn_s_setprio(0);
    SBAR();

    // ---- phase 2: exp0, kk1 (reload af).
#pragma unroll
    for (int m = 0; m < 4; ++m)
      af[m] = *reinterpret_cast<const bf16x8*>(Ab + (arow0 + m * 16) * 128 + cb1);
#pragma unroll
    for (int n = 0; n < 2; ++n)
      bfr[n] = *reinterpret_cast<const bf16x8*>(B0b + (brow0 + n * 16) * 128 + cb1);
    SBAR();
    LGKM0();
    __builtin_amdgcn_s_setprio(1);
#pragma unroll
    for (int m = 0; m < 4; ++m)
#pragma unroll
      for (int n = 0; n < 2; ++n)
        acc0[m][n] = __builtin_amdgcn_mfma_f32_16x16x32_bf16(af[m], bfr[n], acc0[m][n], 0, 0, 0);
    __builtin_amdgcn_s_setprio(0);
    SBAR();

    // ---- phase 3: exp1, kk1. Issue t+2's A+B0 into buf b (A/B0 dead after
    // phase 2's barrier; disjoint from B1[b] being read here). Counted wait.
#pragma unroll
    for (int n = 0; n < 2; ++n)
      bfr[n] = *reinterpret_cast<const bf16x8*>(B1b + (brow0 + n * 16) * 128 + cb1);
    if (kt + 2 < NT) STAGE_AB0(b, kt + 2);
    SBAR();
    LGKM0();
    __builtin_amdgcn_s_setprio(1);
#pragma unroll
    for (int m = 0; m < 4; ++m)
#pragma unroll
      for (int n = 0; n < 2; ++n)
        acc1[m][n] = __builtin_amdgcn_mfma_f32_16x16x32_bf16(af[m], bfr[n], acc1[m][n], 0, 0, 0);
    __builtin_amdgcn_s_setprio(0);
    if (kt + 2 < NT) asm volatile("s_waitcnt vmcnt(5)" ::: "memory");
    else             asm volatile("s_waitcnt vmcnt(0)" ::: "memory");
    SBAR();
  }

  // epilogue: single store, both experts combined
  float bb0[2], bb1[2];
#pragma unroll
  for (int n = 0; n < 2; ++n) {
    int col = fcol + n * 16 + (lane & 15);
    bb0[n] = bias[e0 * ODIM + col];
    bb1[n] = bias[e1 * ODIM + col];
  }

#pragma unroll
  for (int m = 0; m < 4; ++m) {
#pragma unroll
    for (int r = 0; r < 4; ++r) {
      int rl = wr * 64 + m * 16 + (lane >> 4) * 4 + r;
      int t = rowsS[rl];
      if (t < 0) continue;
      float2 w = wgtS[rl];
      size_t o = (size_t)t * ODIM + fcol + (lane & 15);
#pragma unroll
      for (int n = 0; n < 2; ++n)
        out[o + n * 16] = w.x * (acc0[m][n][r] + bb0[n]) + w.y * (acc1[m][n][r] + bb1[n]);
    }
  }
#undef STAGE_AB0
#undef STAGE_B1
#undef SBAR
#undef LGKM0
}

extern "C" void kernel_launch(void* const* d_in, const int* in_sizes, int n_in,
                              void* d_out, int out_size, void* d_ws, size_t ws_size,
                              hipStream_t stream) {
  const float* x    = (const float*)d_in[0];
  const float* ew   = (const float*)d_in[1];
  const int*   tki  = (const int*)d_in[2];
  const float* W    = (const float*)d_in[3];
  const float* bias = (const float*)d_in[4];
  float* out = (float*)d_out;

  char* ws = (char*)d_ws;
  u16*    xb   = (u16*)ws;                               // 67,108,864 B
  u16*    wt   = (u16*)(ws + 67108864);                  //  8,388,608 B
  int*    ctrl = (int*)(ws + 75497472);                  //       128 B
  int*    perm = (int*)(ws + 75497728);                  //   147,456 B
  float2* wgt2 = (float2*)(ws + 75645184);               //   294,912 B -> end 75,940,096

  init_ctrl<<<64, 256, 0, stream>>>(ctrl, perm);
  cvt_x<<<4096, 256, 0, stream>>>((const float4*)x, (uint4*)xb, M_TOK * DIM / 8);
  cvt_wt<<<dim3(KTOT / 32, ODIM / 32), dim3(32, 8), 0, stream>>>(W, wt);
  hist<<<128, 256, 0, stream>>>(tki, ctrl);
  plan<<<1, 64, 0, stream>>>(ctrl);
  scatter<<<128, 256, 0, stream>>>(tki, ew, ctrl, perm, wgt2);
  moe_gemm<<<GEMM_GRID, 512, 0, stream>>>(xb, wt, perm, wgt2, tki, bias, out);
}

// Round 15
// 189.661 us; speedup vs baseline: 1.4950x; 1.4950x over previous
//
#include <hip/hip_runtime.h>
#include <hip/hip_bf16.h>
#include <stdint.h>

#define M_TOK 32768
#define DIM   1024
#define ODIM  1024
#define NEXP  4
#define KTOT  4096            // NEXP * DIM (Wt row length)
#define NBIN  16              // expert-pair groups (e0*4+e1)
#define MTILES 272            // ceil((32768 + 16*127)/128) rounded to mult of 8
#define PERM_LEN (MTILES * 128)   // 34816
#define GEMM_GRID (8 * 34 * 16)   // 8 xcd * 34 mtiles/xcd * 16 nblk = 4352

// fused pre-pass block ranges
#define NB_CVTX 4096
#define NB_CVTW 4096
#define NB_HIST 128
#define NB_PRE  (NB_CVTX + NB_CVTW + NB_HIST)

typedef unsigned short u16;
typedef __bf16 bf16x8 __attribute__((ext_vector_type(8)));
typedef float  f32x4  __attribute__((ext_vector_type(4)));

__device__ inline u16 f2bf(float f) {
  union { float f; unsigned u; } v; v.f = f;
  unsigned u = v.u;
  unsigned r = u + 0x7FFFu + ((u >> 16) & 1u);
  return (u16)(r >> 16);
}

__device__ inline unsigned pack2(float lo, float hi) {
  return (unsigned)f2bf(lo) | ((unsigned)f2bf(hi) << 16);
}

__device__ inline void async16(const void* g, void* l) {
  __builtin_amdgcn_global_load_lds(
      (const __attribute__((address_space(1))) unsigned int*)g,
      (__attribute__((address_space(3))) unsigned int*)l, 16, 0, 0);
}

// ---- fused pre-pass: [0,4096) cvt_x | [4096,8192) cvt_wt | [8192,8320) hist
// ctrl must be pre-zeroed (hipMemsetAsync).
__global__ void pre_pass(const float* __restrict__ x, uint4* __restrict__ xb,
                         const float* __restrict__ W, u16* __restrict__ Wt,
                         const int* __restrict__ tki, int* __restrict__ ctrl) {
  __shared__ float t[32][33];
  __shared__ int h[NBIN];
  const int b = blockIdx.x, tid = threadIdx.x;

  if (b < NB_CVTX) {
    // x fp32 -> bf16, 8 elems/thread/iter
    const float4* xv = (const float4*)x;
    const int n8 = M_TOK * DIM / 8;
    for (int i = b * 256 + tid; i < n8; i += NB_CVTX * 256) {
      float4 a = xv[2 * i];
      float4 c = xv[2 * i + 1];
      uint4 o;
      o.x = pack2(a.x, a.y); o.y = pack2(a.z, a.w);
      o.z = pack2(c.x, c.y); o.w = pack2(c.z, c.w);
      xb[i] = o;
    }
  } else if (b < NB_CVTX + NB_CVTW) {
    // W (E*D, O) fp32 -> Wt (O, E*D) bf16, 32x32 tile transpose
    const int bb = b - NB_CVTX;
    const int kk0 = (bb & 127) * 32, n0 = (bb >> 7) * 32;
    const int tx = tid & 31, ty = tid >> 5;   // (32,8)
#pragma unroll
    for (int j = 0; j < 32; j += 8)
      t[ty + j][tx] = W[(size_t)(kk0 + ty + j) * ODIM + n0 + tx];
    __syncthreads();
#pragma unroll
    for (int j = 0; j < 32; j += 8)
      Wt[(size_t)(n0 + ty + j) * KTOT + kk0 + tx] = f2bf(t[tx][ty + j]);
  } else {
    // expert-pair histogram
    const int bb = b - NB_CVTX - NB_CVTW;
    if (tid < NBIN) h[tid] = 0;
    __syncthreads();
    int tok = bb * 256 + tid;   // 128 blocks x 256 = 32768 tokens
    int e0 = tki[2 * tok] & 3, e1 = tki[2 * tok + 1] & 3;
    atomicAdd(&h[e0 * 4 + e1], 1);
    __syncthreads();
    if (tid < NBIN) atomicAdd(&ctrl[tid], h[tid]);
  }
}

// ---- scatter w/ local plan: offsets computed per-block from final counts;
// global cursors at ctrl[16..31] (pre-zeroed by memset).
__global__ void scatter(const int* __restrict__ tki, const float* __restrict__ ew,
                        int* __restrict__ ctrl,
                        int* __restrict__ perm, float2* __restrict__ wgt2) {
  __shared__ int h[NBIN], gbase[NBIN], cur[NBIN], offs[NBIN];
  int tid = threadIdx.x;
  if (tid < NBIN) { h[tid] = 0; cur[tid] = 0; }
  if (tid == 0) {
    int off = 0;
#pragma unroll
    for (int b = 0; b < NBIN; ++b) {
      offs[b] = off;
      off += (ctrl[b] + 127) & ~127;   // pad each pair-group to 128 rows
    }
  }
  __syncthreads();
  int t = blockIdx.x * 256 + tid;
  int e0 = tki[2 * t] & 3, e1 = tki[2 * t + 1] & 3;
  int bin = e0 * 4 + e1;
  atomicAdd(&h[bin], 1);
  __syncthreads();
  if (tid < NBIN && h[tid] > 0)
    gbase[tid] = offs[tid] + atomicAdd(&ctrl[16 + tid], h[tid]);
  __syncthreads();
  int rank = atomicAdd(&cur[bin], 1);
  int pos = gbase[bin] + rank;
  perm[pos] = t;
  float2 w; w.x = ew[2 * t]; w.y = ew[2 * t + 1];
  wgt2[pos] = w;
}

// ---- fused single-pass grouped GEMM: out[t] = w0*(x@W_e0+b_e0) + w1*(x@W_e1+b_e1)
// (verified round-13 kernel, unchanged). Tokens grouped by expert PAIR.
// 128 tok x 64 N-cols per block, 256 thr = 4 waves (2x2), wave-tile 64x32
// per expert, acc0+acc1 = 64 regs. 2-barrier template: 8 async16 : 32 MFMA
// per K-step, XOR swizzle. XCD remap: each XCD owns a contiguous run of 34
// mtiles (bin-sorted perm => concurrent mtiles share one 4MB W-panel in L2);
// 16 nblk of one mtile concurrent on the XCD => A-panel reuse.
__global__ __launch_bounds__(256, 4) void moe_gemm(
    const u16* __restrict__ Xb,       // [M_TOK][DIM] bf16
    const u16* __restrict__ Wt,       // [ODIM][KTOT] bf16
    const int* __restrict__ perm,     // [PERM_LEN] token ids (-1 pad)
    const float2* __restrict__ wgt2,  // [PERM_LEN] (w0,w1)
    const int* __restrict__ tki,      // [M_TOK][2] expert ids
    const float* __restrict__ bias,   // [NEXP][ODIM] fp32
    float* __restrict__ out)          // [M_TOK][ODIM] fp32
{
  __shared__ __align__(16) u16 As [128 * 64];   // 16 KB
  __shared__ __align__(16) u16 Bs0[64 * 64];    // 8 KB
  __shared__ __align__(16) u16 Bs1[64 * 64];    // 8 KB
  __shared__ int    rowsS[128];
  __shared__ float2 wgtS[128];

  const int d = blockIdx.x;
  const int slot = d >> 3;                  // 0..543 per XCD
  const int mtile = (d & 7) * (MTILES / 8) + (slot >> 4);
  const int nblk = slot & 15;               // 16 N-blocks of 64 cols
  const int base = mtile * 128;
  const int t0 = perm[base];
  if (t0 < 0) return;                       // fully-padding tile (uniform)
  const int e0 = tki[2 * t0] & 3, e1 = tki[2 * t0 + 1] & 3;

  const int tid = threadIdx.x;
  if (tid < 128) { rowsS[tid] = perm[base + tid]; wgtS[tid] = wgt2[base + tid]; }

  const int wid = tid >> 6, lane = tid & 63;
  const int bcol = nblk * 64;
  const int wr = wid >> 1, wc = wid & 1;    // 2x2 waves; wave-tile 64 rows x 32 cols
  const int fcol = bcol + wc * 32;

  f32x4 acc0[4][2], acc1[4][2];
#pragma unroll
  for (int m = 0; m < 4; ++m)
#pragma unroll
    for (int n = 0; n < 2; ++n) {
      acc0[m][n] = (f32x4){0.f, 0.f, 0.f, 0.f};
      acc1[m][n] = (f32x4){0.f, 0.f, 0.f, 0.f};
    }

  const int srow = lane >> 3;                // 0..7
  const int scol = ((lane & 7) ^ srow) * 8;  // pre-swizzled source col
  const int hi16 = (lane >> 4) * 16;
  const int swz  = (lane & 7) << 4;
  const char* AsB  = (const char*)As;
  const char* Bs0B = (const char*)Bs0;
  const char* Bs1B = (const char*)Bs1;

  __syncthreads();                           // rowsS/wgtS ready

  // staging base pointers: 4 A-chunks + 2 B0-chunks + 2 B1-chunks per wave
  const u16* aptr[4];
  const u16* b0ptr[2];
  const u16* b1ptr[2];
#pragma unroll
  for (int i = 0; i < 4; ++i) {
    int c = wid * 4 + i;                     // 0..15: A rows c*8+srow (0..127)
    int r = rowsS[c * 8 + srow];
    if (r < 0) r = 0;                        // pad row: stage row 0, discard later
    aptr[i] = Xb + (size_t)r * DIM + scol;
  }
#pragma unroll
  for (int i = 0; i < 2; ++i) {
    int c = wid * 2 + i;                     // 0..7: B rows c*8+srow (0..63)
    size_t wrow = (size_t)(bcol + c * 8 + srow) * KTOT + scol;
    b0ptr[i] = Wt + wrow + e0 * DIM;
    b1ptr[i] = Wt + wrow + e1 * DIM;
  }

  for (int kt = 0; kt < DIM / 64; ++kt) {    // 16 K-steps
    __syncthreads();
#pragma unroll
    for (int i = 0; i < 4; ++i)
      async16(aptr[i] + kt * 64, &As[(wid * 4 + i) * 512]);
#pragma unroll
    for (int i = 0; i < 2; ++i) {
      async16(b0ptr[i] + kt * 64, &Bs0[(wid * 2 + i) * 512]);
      async16(b1ptr[i] + kt * 64, &Bs1[(wid * 2 + i) * 512]);
    }
    __syncthreads();
#pragma unroll
    for (int kk = 0; kk < 2; ++kk) {
      const int cb = (kk * 64 + hi16) ^ swz;
      bf16x8 af[4], bf0[2], bf1[2];
#pragma unroll
      for (int m = 0; m < 4; ++m) {
        int row = wr * 64 + m * 16 + (lane & 15);
        af[m] = *reinterpret_cast<const bf16x8*>(AsB + row * 128 + cb);
      }
#pragma unroll
      for (int n = 0; n < 2; ++n) {
        int row = wc * 32 + n * 16 + (lane & 15);
        bf0[n] = *reinterpret_cast<const bf16x8*>(Bs0B + row * 128 + cb);
        bf1[n] = *reinterpret_cast<const bf16x8*>(Bs1B + row * 128 + cb);
      }
#pragma unroll
      for (int m = 0; m < 4; ++m)
#pragma unroll
        for (int n = 0; n < 2; ++n) {
          acc0[m][n] = __builtin_amdgcn_mfma_f32_16x16x32_bf16(af[m], bf0[n], acc0[m][n], 0, 0, 0);
          acc1[m][n] = __builtin_amdgcn_mfma_f32_16x16x32_bf16(af[m], bf1[n], acc1[m][n], 0, 0, 0);
        }
    }
  }

  // epilogue: single store, both experts combined
  float bb0[2], bb1[2];
#pragma unroll
  for (int n = 0; n < 2; ++n) {
    int col = fcol + n * 16 + (lane & 15);
    bb0[n] = bias[e0 * ODIM + col];
    bb1[n] = bias[e1 * ODIM + col];
  }

#pragma unroll
  for (int m = 0; m < 4; ++m) {
#pragma unroll
    for (int r = 0; r < 4; ++r) {
      int rl = wr * 64 + m * 16 + (lane >> 4) * 4 + r;
      int t = rowsS[rl];
      if (t < 0) continue;
      float2 w = wgtS[rl];
      size_t o = (size_t)t * ODIM + fcol + (lane & 15);
#pragma unroll
      for (int n = 0; n < 2; ++n)
        out[o + n * 16] = w.x * (acc0[m][n][r] + bb0[n]) + w.y * (acc1[m][n][r] + bb1[n]);
    }
  }
}

extern "C" void kernel_launch(void* const* d_in, const int* in_sizes, int n_in,
                              void* d_out, int out_size, void* d_ws, size_t ws_size,
                              hipStream_t stream) {
  const float* x    = (const float*)d_in[0];
  const float* ew   = (const float*)d_in[1];
  const int*   tki  = (const int*)d_in[2];
  const float* W    = (const float*)d_in[3];
  const float* bias = (const float*)d_in[4];
  float* out = (float*)d_out;

  char* ws = (char*)d_ws;
  u16*    xb   = (u16*)ws;                               // 67,108,864 B
  u16*    wt   = (u16*)(ws + 67108864);                  //  8,388,608 B
  int*    ctrl = (int*)(ws + 75497472);                  //       128 B
  int*    perm = (int*)(ws + 75497728);                  //   139,264 B
  float2* wgt2 = (float2*)(ws + 75636992);               //   278,528 B -> end 75,915,520

  hipMemsetAsync(ctrl, 0, 128, stream);                     // counts + cursors
  hipMemsetAsync(perm, 0xFF, PERM_LEN * sizeof(int), stream); // perm = -1
  pre_pass<<<NB_PRE, 256, 0, stream>>>(x, (uint4*)xb, W, wt, tki, ctrl);
  scatter<<<128, 256, 0, stream>>>(tki, ew, ctrl, perm, wgt2);
  moe_gemm<<<GEMM_GRID, 256, 0, stream>>>(xb, wt, perm, wgt2, tki, bias, out);
}